// Round 6
// baseline (401.986 us; speedup 1.0000x reference)
//
#include <hip/hip_runtime.h>
#include <hip/hip_bf16.h>

#define NN   207
#define BB   8
#define TT   12
#define EE   64
#define FFD  256
#define NGH  8
#define GALPHA 0.2f
#define GNEG  -9e15f

__device__ __forceinline__ float wred_max(float v) {
#pragma unroll
  for (int o = 32; o >= 1; o >>= 1) v = fmaxf(v, __shfl_xor(v, o));
  return v;
}
__device__ __forceinline__ float wred_sum(float v) {
#pragma unroll
  for (int o = 32; o >= 1; o >>= 1) v += __shfl_xor(v, o);
  return v;
}
__device__ __forceinline__ float lo_f(unsigned u) { return __uint_as_float(u << 16); }
__device__ __forceinline__ float hi_f(unsigned u) { return __uint_as_float(u & 0xffff0000u); }
__device__ __forceinline__ unsigned pk2(float a, float b) {
  unsigned la = (unsigned)__bfloat16_as_ushort(__float2bfloat16(a));
  unsigned lb = (unsigned)__bfloat16_as_ushort(__float2bfloat16(b));
  return la | (lb << 16);
}
__device__ __forceinline__ unsigned short bf16u(float a) {
  return __bfloat16_as_ushort(__float2bfloat16(a));
}
#define UNPK8(U, f) { (f)[0]=lo_f((U).x); (f)[1]=hi_f((U).x); (f)[2]=lo_f((U).y); (f)[3]=hi_f((U).y); \
                      (f)[4]=lo_f((U).z); (f)[5]=hi_f((U).z); (f)[6]=lo_f((U).w); (f)[7]=hi_f((U).w); }

// ===========================================================================
// Kernel A: GAT (8 heads) + conv1. One block per (b, n). Writes out0 (B,N,T,E).
// ===========================================================================
#define A_GW 2484   // u32 xs_pk[12][207] then 96 floats of GAT params

__global__ __launch_bounds__(256) void gat_conv1_kernel(
    const float* __restrict__ x,        const int* __restrict__ adj,
    const float* __restrict__ gat_W2,   const float* __restrict__ gat_a,
    const float* __restrict__ gat_b,    const float* __restrict__ conv1_w,
    const float* __restrict__ conv1_b,  float* __restrict__ out0)
{
  __shared__ float lds[A_GW + 96];
  unsigned* au = (unsigned*)lds;

  const int bn   = blockIdx.x;
  const int b    = bn / NN;
  const int i    = bn % NN;
  const int tid  = threadIdx.x;
  const int lane = tid & 63;
  const int wid  = tid >> 6;

  const float* xb = x + b * 2 * NN * TT;
  for (int idx = tid; idx < NN * TT; idx += 256) {
    const int n = idx / TT, t = idx % TT;
    au[t * NN + n] = pk2(xb[idx], xb[NN * TT + idx]);
  }
  if (tid < 64) lds[A_GW + tid] = gat_W2[tid];
  if (tid < 16) { lds[A_GW + 64 + tid] = gat_a[tid]; lds[A_GW + 80 + tid] = gat_b[tid]; }
  __syncthreads();

  int   row0[4], row1[4];
  float aokf[4];
  bool  jv[4];
  {
    const int NSQ = NN * NN;
#pragma unroll
    for (int q = 0; q < 4; ++q) {
      const int j = lane + 64 * q;
      jv[q] = (j < NN);
      const int jj = jv[q] ? j : 0;
      const int r0 = 2 * (i * NN + jj), r1 = r0 + 1;
      row0[q] = (r0 < NSQ) ? (r0 / NN) : ((r0 - NSQ) % NN);
      row1[q] = (r1 < NSQ) ? (r1 / NN) : ((r1 - NSQ) % NN);
      aokf[q] = (jv[q] && adj[(b * NN + i) * NN + jj] > 0) ? 1.f : 0.f;
    }
  }

  float acc0[3] = {0.f, 0.f, 0.f}, acc1[3] = {0.f, 0.f, 0.f};
#pragma unroll
  for (int tk = 0; tk < 3; ++tk) {
    const int t = wid + 4 * tk;
    const unsigned* xst = au + t * NN;
    float xr00[4], xr01[4], xr10[4], xr11[4], xj0[4], xj1[4];
#pragma unroll
    for (int q = 0; q < 4; ++q) {
      const int j = jv[q] ? (lane + 64 * q) : 0;
      const unsigned u0 = xst[row0[q]], u1 = xst[row1[q]], uj = xst[j];
      xr00[q] = lo_f(u0); xr01[q] = hi_f(u0);
      xr10[q] = lo_f(u1); xr11[q] = hi_f(u1);
      xj0[q]  = lo_f(uj); xj1[q]  = hi_f(uj);
    }
    for (int h = 0; h < NGH; ++h) {
      const float w0 = lds[A_GW + h*8 + 0], w1_ = lds[A_GW + h*8 + 1];
      const float w2_= lds[A_GW + h*8 + 2], w3  = lds[A_GW + h*8 + 3];
      const float w4 = lds[A_GW + h*8 + 4], w5  = lds[A_GW + h*8 + 5];
      const float w6 = lds[A_GW + h*8 + 6], w7  = lds[A_GW + h*8 + 7];
      const float a0 = lds[A_GW + 64 + h*2], a1 = lds[A_GW + 64 + h*2 + 1];
      float ev[4];
#pragma unroll
      for (int q = 0; q < 4; ++q) {
        float wx0 = xr00[q]*w0 + xr01[q]*w2_ + xr10[q]*w4 + xr11[q]*w6;
        float wx1 = xr00[q]*w1_ + xr01[q]*w3 + xr10[q]*w5 + xr11[q]*w7;
        wx0 = (wx0 > 0.f) ? wx0 : GALPHA * wx0;
        wx1 = (wx1 > 0.f) ? wx1 : GALPHA * wx1;
        float e = a0 * wx0 + a1 * wx1;
        e = (aokf[q] > 0.f) ? e : GNEG;
        ev[q] = jv[q] ? e : -INFINITY;
      }
      float m = fmaxf(fmaxf(ev[0], ev[1]), fmaxf(ev[2], ev[3]));
      m = wred_max(m);
      float s0 = 0.f, s1 = 0.f, s2 = 0.f;
#pragma unroll
      for (int q = 0; q < 4; ++q) {
        const float ex = jv[q] ? __expf(ev[q] - m) : 0.f;
        s0 += ex; s1 += ex * xj0[q]; s2 += ex * xj1[q];
      }
      s0 = wred_sum(s0); s1 = wred_sum(s1); s2 = wred_sum(s2);
      const float inv = 1.f / s0;
      acc0[tk] += tanhf(s1 * inv + lds[A_GW + 80 + h*2]);
      acc1[tk] += tanhf(s2 * inv + lds[A_GW + 80 + h*2 + 1]);
    }
  }

  // conv1 epilogue -> out0[bn][t][e]
  {
    const float c1w0 = conv1_w[lane],       c1w1 = conv1_w[64 + lane];
    const float c1w2 = conv1_w[128 + lane], c1w3 = conv1_w[192 + lane];
    const float c1b  = conv1_b[lane];
#pragma unroll
    for (int tk = 0; tk < 3; ++tk) {
      const int t = wid + 4 * tk;
      const unsigned up = au[t * NN + i];
      const float g0 = acc0[tk] * (1.f / NGH), g1 = acc1[tk] * (1.f / NGH);
      out0[bn*768 + t*EE + lane] = lo_f(up)*c1w0 + hi_f(up)*c1w1 + g0*c1w2 + g1*c1w3 + c1b;
    }
  }
}

// ===========================================================================
// Kernel B: 2-layer transformer + conv2/conv3. One block per (b, n).
// ===========================================================================
// LDS layout (float units). f32 bufs stride 68, bf16 stride 72.
#define SRD   68
#define SRD16 72
#define L_OUT 0
#define L_QQ  816
#define L_CTX 1632
#define L_X1  2448
#define L_QB  3264   // bf16 [12][72] = 432 u32 slots
#define L_KB  3696
#define L_VB  4128
#define L_SC  4560   // 4 heads * 144
#define L_FF  5136   // bf16 12*[256] = 1536 u32 slots
#define L_PART 6672  // 4*768 f32
#define L_TOT 9744   // 38,976 B

__global__ __launch_bounds__(256) void xf_final_kernel(
    const float* __restrict__ out0,     const float* __restrict__ temb,
    const float* __restrict__ Wq, const float* __restrict__ Wk,
    const float* __restrict__ Wv, const float* __restrict__ Wo,
    const float* __restrict__ bo,
    const float* __restrict__ ln1_g, const float* __restrict__ ln1_b,
    const float* __restrict__ ln2_g, const float* __restrict__ ln2_b,
    const float* __restrict__ ff_w1, const float* __restrict__ ff_b1,
    const float* __restrict__ ff_w2, const float* __restrict__ ff_b2,
    const float* __restrict__ lng, const float* __restrict__ lnb,
    const float* __restrict__ conv2_w, const float* __restrict__ conv2_b,
    const float* __restrict__ conv3_w, const float* __restrict__ conv3_b,
    float* __restrict__ fout)
{
  __shared__ float lds[L_TOT];
  unsigned*       au   = (unsigned*)lds;
  unsigned short* sh16 = (unsigned short*)lds;

  const int bn   = blockIdx.x;
  const int tid  = threadIdx.x;
  const int lane = tid & 63;
  const int wid  = tid >> 6;

  for (int o = tid; o < 768; o += 256) {
    const int t = o >> 6, e = o & 63;
    lds[L_OUT + t*SRD + e] = out0[bn*768 + o];
  }
  __syncthreads();

  for (int l = 0; l < 2; ++l) {
    const float* wq = Wq + l*4096; const float* wk = Wk + l*4096;
    const float* wv = Wv + l*4096; const float* wo = Wo + l*4096;
    const float* w1 = ff_w1 + l*EE*FFD; const float* pb1 = ff_b1 + l*FFD;
    const float* w2 = ff_w2 + l*FFD*EE; const float* pb2 = ff_b2 + l*EE;

    // qq = out + temb
    {
      const int e = tid & 63;
#pragma unroll
      for (int tt = 0; tt < 3; ++tt) {
        const int t = 3*wid + tt;
        lds[L_QQ + t*SRD + e] = lds[L_OUT + t*SRD + e] + temb[t*EE + e];
      }
    }
    __syncthreads();

    // QKV: thread owns col c (of Q,K,V) x t-triple
    {
      const int c = tid & 63;
      float aq[3] = {0,0,0}, ak[3] = {0,0,0}, av[3] = {0,0,0};
      for (int kb = 0; kb < 16; ++kb) {
        float a0v[4], a1v[4], a2v[4];
        *(float4*)a0v = *(const float4*)&lds[L_QQ + (3*wid+0)*SRD + 4*kb];
        *(float4*)a1v = *(const float4*)&lds[L_QQ + (3*wid+1)*SRD + 4*kb];
        *(float4*)a2v = *(const float4*)&lds[L_QQ + (3*wid+2)*SRD + 4*kb];
#pragma unroll
        for (int kk = 0; kk < 4; ++kk) {
          const int k = 4*kb + kk;
          const float wqv = wq[k*EE + c], wkv = wk[k*EE + c], wvv = wv[k*EE + c];
          aq[0] += a0v[kk]*wqv; aq[1] += a1v[kk]*wqv; aq[2] += a2v[kk]*wqv;
          ak[0] += a0v[kk]*wkv; ak[1] += a1v[kk]*wkv; ak[2] += a2v[kk]*wkv;
          av[0] += a0v[kk]*wvv; av[1] += a1v[kk]*wvv; av[2] += a2v[kk]*wvv;
        }
      }
#pragma unroll
      for (int tt = 0; tt < 3; ++tt) {
        const int t = 3*wid + tt;
        sh16[2*L_QB + t*SRD16 + c] = bf16u(aq[tt]);
        sh16[2*L_KB + t*SRD16 + c] = bf16u(ak[tt]);
        sh16[2*L_VB + t*SRD16 + c] = bf16u(av[tt]);
      }
    }
    __syncthreads();

    // Attention: wave h owns head h; wave-local.
    {
      const int h = wid;
      if (lane < 48) {
        const int t = lane >> 2, s0 = 3*(lane & 3);
        float qf[16];
        {
          const uint4 qa = *(const uint4*)&sh16[2*L_QB + t*SRD16 + h*16];
          const uint4 qb = *(const uint4*)&sh16[2*L_QB + t*SRD16 + h*16 + 8];
          UNPK8(qa, qf); UNPK8(qb, qf + 8);
        }
#pragma unroll
        for (int ss = 0; ss < 3; ++ss) {
          const int s = s0 + ss;
          float d = 0.f;
          {
            const uint4 ka = *(const uint4*)&sh16[2*L_KB + s*SRD16 + h*16];
            float kf[8]; UNPK8(ka, kf);
#pragma unroll
            for (int xq = 0; xq < 8; ++xq) d += qf[xq]*kf[xq];
          }
          {
            const uint4 kc = *(const uint4*)&sh16[2*L_KB + s*SRD16 + h*16 + 8];
            float kf[8]; UNPK8(kc, kf);
#pragma unroll
            for (int xq = 0; xq < 8; ++xq) d += qf[8+xq]*kf[xq];
          }
          lds[L_SC + h*144 + t*12 + s] = d * 0.25f;
        }
      }
      __builtin_amdgcn_wave_barrier();
      if (lane < 12) {
        float* row = &lds[L_SC + h*144 + lane*12];
        float m = row[0];
#pragma unroll
        for (int s = 1; s < 12; ++s) m = fmaxf(m, row[s]);
        float ex[12]; float sum = 0.f;
#pragma unroll
        for (int s = 0; s < 12; ++s) { ex[s] = __expf(row[s] - m); sum += ex[s]; }
        const float inv = 1.f / sum;
#pragma unroll
        for (int s = 0; s < 12; ++s) row[s] = ex[s] * inv;
      }
      __builtin_amdgcn_wave_barrier();
      {
        const int d = lane & 15, tq = lane >> 4;
#pragma unroll
        for (int tt = 0; tt < 3; ++tt) {
          const int t = tq + 4*tt;
          float cacc = 0.f;
#pragma unroll
          for (int s = 0; s < 12; ++s) {
            const float p = lds[L_SC + h*144 + t*12 + s];
            const unsigned uv = au[L_VB + s*36 + h*8 + (d >> 1)];
            cacc += p * ((d & 1) ? hi_f(uv) : lo_f(uv));
          }
          lds[L_CTX + t*SRD + h*16 + d] = cacc;
        }
      }
    }
    __syncthreads();

    // Wo + bias + residual(qq) -> X1
    {
      const int e = tid & 63;
      float acc[3] = {0,0,0};
      for (int kb = 0; kb < 16; ++kb) {
        float a0v[4], a1v[4], a2v[4];
        *(float4*)a0v = *(const float4*)&lds[L_CTX + (3*wid+0)*SRD + 4*kb];
        *(float4*)a1v = *(const float4*)&lds[L_CTX + (3*wid+1)*SRD + 4*kb];
        *(float4*)a2v = *(const float4*)&lds[L_CTX + (3*wid+2)*SRD + 4*kb];
#pragma unroll
        for (int kk = 0; kk < 4; ++kk) {
          const float wov = wo[(4*kb+kk)*EE + e];
          acc[0] += a0v[kk]*wov; acc[1] += a1v[kk]*wov; acc[2] += a2v[kk]*wov;
        }
      }
#pragma unroll
      for (int tt = 0; tt < 3; ++tt) {
        const int t = 3*wid + tt;
        lds[L_X1 + t*SRD + e] = acc[tt] + bo[l*EE + e] + lds[L_QQ + t*SRD + e];
      }
    }
    __syncthreads();

    // LN1
    for (int tk = 0; tk < 3; ++tk) {
      const int t = wid + 4*tk;
      float v = lds[L_X1 + t*SRD + lane];
      const float mu = wred_sum(v) * (1.f/64);
      const float d = v - mu;
      const float var = wred_sum(d*d) * (1.f/64);
      lds[L_X1 + t*SRD + lane] = d * rsqrtf(var + 1e-5f) * ln1_g[l*EE + lane] + ln1_b[l*EE + lane];
    }
    __syncthreads();

    // FF1 + relu -> ff (bf16). Two passes of f-pairs (lower live pressure).
    {
      for (int p = 0; p < 2; ++p) {
        const int f0 = 4*(tid & 63) + 2*p;
        float ac0[2] = {0,0}, ac1[2] = {0,0}, ac2[2] = {0,0};
        for (int kb = 0; kb < 16; ++kb) {
          float a0v[4], a1v[4], a2v[4];
          *(float4*)a0v = *(const float4*)&lds[L_X1 + (3*wid+0)*SRD + 4*kb];
          *(float4*)a1v = *(const float4*)&lds[L_X1 + (3*wid+1)*SRD + 4*kb];
          *(float4*)a2v = *(const float4*)&lds[L_X1 + (3*wid+2)*SRD + 4*kb];
#pragma unroll
          for (int kk = 0; kk < 4; ++kk) {
            const float2 wv = *(const float2*)&w1[(4*kb+kk)*FFD + f0];
            ac0[0] += a0v[kk]*wv.x; ac0[1] += a0v[kk]*wv.y;
            ac1[0] += a1v[kk]*wv.x; ac1[1] += a1v[kk]*wv.y;
            ac2[0] += a2v[kk]*wv.x; ac2[1] += a2v[kk]*wv.y;
          }
        }
        const float2 bv = *(const float2*)&pb1[f0];
#pragma unroll
        for (int tt = 0; tt < 3; ++tt) {
          const int t = 3*wid + tt;
          const float* ac = (tt == 0) ? ac0 : (tt == 1) ? ac1 : ac2;
          au[L_FF + t*128 + (f0 >> 1)] = pk2(fmaxf(ac[0] + bv.x, 0.f),
                                            fmaxf(ac[1] + bv.y, 0.f));
        }
      }
    }
    __syncthreads();

    // FF2: wave = k-slice of 64; 4-k chunks (b64 reads, low pressure)
    {
      const int e0 = 2 * (lane & 31);
      const int th = lane >> 5;
      float acc[6][2] = {};
      for (int c = 0; c < 16; ++c) {
        float2 wv2[4];
#pragma unroll
        for (int kk = 0; kk < 4; ++kk)
          wv2[kk] = *(const float2*)&w2[(wid*64 + c*4 + kk)*EE + e0];
#pragma unroll
        for (int tt = 0; tt < 6; ++tt) {
          const int t = th*6 + tt;
          const uint2 U = *(const uint2*)&au[L_FF + t*128 + wid*32 + c*2];
          float fv[4];
          fv[0]=lo_f(U.x); fv[1]=hi_f(U.x); fv[2]=lo_f(U.y); fv[3]=hi_f(U.y);
#pragma unroll
          for (int kk = 0; kk < 4; ++kk) {
            acc[tt][0] += fv[kk]*wv2[kk].x;
            acc[tt][1] += fv[kk]*wv2[kk].y;
          }
        }
      }
#pragma unroll
      for (int tt = 0; tt < 6; ++tt) {
        const int t = th*6 + tt;
        *(float2*)&lds[L_PART + wid*768 + t*EE + e0] = make_float2(acc[tt][0], acc[tt][1]);
      }
    }
    __syncthreads();

    // combine partials + b2 + residual(x1) ; LN2 ; out = LN3(blk + out)
    for (int tk = 0; tk < 3; ++tk) {
      const int t = wid + 4*tk;
      float v = lds[L_PART + t*EE + lane] + lds[L_PART + 768 + t*EE + lane]
              + lds[L_PART + 1536 + t*EE + lane] + lds[L_PART + 2304 + t*EE + lane]
              + pb2[lane] + lds[L_X1 + t*SRD + lane];
      float mu = wred_sum(v) * (1.f/64);
      float d = v - mu;
      float var = wred_sum(d*d) * (1.f/64);
      const float blk = d * rsqrtf(var + 1e-5f) * ln2_g[l*EE + lane] + ln2_b[l*EE + lane];
      float w = blk + lds[L_OUT + t*SRD + lane];
      mu = wred_sum(w) * (1.f/64);
      d = w - mu;
      var = wred_sum(d*d) * (1.f/64);
      lds[L_OUT + t*SRD + lane] = d * rsqrtf(var + 1e-5f) * lng[l*EE + lane] + lnb[l*EE + lane];
    }
    __syncthreads();
  }

  // final conv2 (time mix) + relu + conv3 (embed contraction)
  float xt[12];
#pragma unroll
  for (int t = 0; t < 12; ++t) xt[t] = lds[L_OUT + t*SRD + lane];
  const float c3w = conv3_w[lane];
  for (int o = wid; o < 12; o += 4) {
    float a = conv2_b[o];
#pragma unroll
    for (int t = 0; t < 12; ++t) a += xt[t] * conv2_w[o*TT + t];
    a = fmaxf(a, 0.f);
    const float s = wred_sum(a * c3w);
    if (lane == 0) fout[bn*TT + o] = s + conv3_b[0];
  }
}

// ---------------------------------------------------------------------------
extern "C" void kernel_launch(void* const* d_in, const int* in_sizes, int n_in,
                              void* d_out, int out_size, void* d_ws, size_t ws_size,
                              hipStream_t stream) {
  const float* x       = (const float*)d_in[0];
  const int*   adj     = (const int*)  d_in[1];
  const float* gat_W2  = (const float*)d_in[2];
  const float* gat_a   = (const float*)d_in[3];
  const float* gat_b   = (const float*)d_in[4];
  const float* conv1_w = (const float*)d_in[5];
  const float* conv1_b = (const float*)d_in[6];
  const float* temb    = (const float*)d_in[7];
  const float* Wq      = (const float*)d_in[8];
  const float* Wk      = (const float*)d_in[9];
  const float* Wv      = (const float*)d_in[10];
  const float* Wo      = (const float*)d_in[11];
  const float* bo      = (const float*)d_in[12];
  const float* ln1_g   = (const float*)d_in[13];
  const float* ln1_b   = (const float*)d_in[14];
  const float* ln2_g   = (const float*)d_in[15];
  const float* ln2_b   = (const float*)d_in[16];
  const float* ff_w1   = (const float*)d_in[17];
  const float* ff_b1   = (const float*)d_in[18];
  const float* ff_w2   = (const float*)d_in[19];
  const float* ff_b2   = (const float*)d_in[20];
  const float* lng     = (const float*)d_in[21];
  const float* lnb     = (const float*)d_in[22];
  const float* conv2_w = (const float*)d_in[23];
  const float* conv2_b = (const float*)d_in[24];
  const float* conv3_w = (const float*)d_in[25];
  const float* conv3_b = (const float*)d_in[26];

  float* out0 = (float*)d_ws;   // (B,N,T,E) f32 = 5.09 MB
  float* fout = (float*)d_out;

  gat_conv1_kernel<<<BB*NN, 256, 0, stream>>>(
      x, adj, gat_W2, gat_a, gat_b, conv1_w, conv1_b, out0);

  xf_final_kernel<<<BB*NN, 256, 0, stream>>>(
      out0, temb, Wq, Wk, Wv, Wo, bo, ln1_g, ln1_b, ln2_g, ln2_b,
      ff_w1, ff_b1, ff_w2, ff_b2, lng, lnb,
      conv2_w, conv2_b, conv3_w, conv3_b, fout);
}

// Round 8
// 302.716 us; speedup vs baseline: 1.3279x; 1.3279x over previous
//
#include <hip/hip_runtime.h>
#include <hip/hip_bf16.h>

#define NN   207
#define BB   8
#define TT   12
#define EE   64
#define FFD  256
#define NGH  8
#define GALPHA 0.2f
#define GNEG  -9e15f

// ---- Kernel B LDS layout (f32 units) ----
#define SRD   68      // f32 row stride (bank-safe, 16B-aligned)
#define SRD16 72      // bf16 row stride (u16 units)
#define FSRD  264     // FF f32 row stride
#define L_QQ  0       // [12][68]
#define L_X1  816     // [12][68]
#define L_QB  1632    // bf16 [12][72] (u16@2*L_QB)
#define L_KB  2064
#define L_VB  2496
#define L_SC  2928    // 4 heads * 144
#define L_CTX 3504    // [12][68] -> ends 4320
#define L_FF  1632    // alias over QB..CTX (dead there), [12][264] -> ends 4800
#define L_TOTB 4800   // 19200 B

__device__ __forceinline__ float wred_max(float v) {
#pragma unroll
  for (int o = 32; o >= 1; o >>= 1) v = fmaxf(v, __shfl_xor(v, o));
  return v;
}
__device__ __forceinline__ float wred_sum(float v) {
#pragma unroll
  for (int o = 32; o >= 1; o >>= 1) v += __shfl_xor(v, o);
  return v;
}
__device__ __forceinline__ float lo_f(unsigned u) { return __uint_as_float(u << 16); }
__device__ __forceinline__ float hi_f(unsigned u) { return __uint_as_float(u & 0xffff0000u); }
__device__ __forceinline__ float b16f(unsigned short s) { return __uint_as_float(((unsigned)s) << 16); }
__device__ __forceinline__ unsigned pk2(float a, float b) {
  unsigned la = (unsigned)__bfloat16_as_ushort(__float2bfloat16(a));
  unsigned lb = (unsigned)__bfloat16_as_ushort(__float2bfloat16(b));
  return la | (lb << 16);
}
__device__ __forceinline__ unsigned short bf16u(float a) {
  return __bfloat16_as_ushort(__float2bfloat16(a));
}
__device__ __forceinline__ float tanh_fast(float x) {
  // exact identity: tanh(x) = 1 - 2/(e^{2x}+1); inf-safe both directions
  return 1.f - 2.f / (__expf(2.f * x) + 1.f);
}
#define UNPK8(U, f) { (f)[0]=lo_f((U).x); (f)[1]=hi_f((U).x); (f)[2]=lo_f((U).y); (f)[3]=hi_f((U).y); \
                      (f)[4]=lo_f((U).z); (f)[5]=hi_f((U).z); (f)[6]=lo_f((U).w); (f)[7]=hi_f((U).w); }

// ===========================================================================
// Workspace layout (u16 units from d_ws base):
//   wb   : [0 .. 98304)        bf16 transposed weights (196,608 B)
//   out0 : [98304 .. 1370112)  bf16 (B,N,T,E) residual-stream input
// Total 2.74 MB (< 5.09 MB known-good watermark).
// ===========================================================================

// ===========================================================================
// Prep: bf16 transposed+kb-tiled weights into ws.
// Layout (u16 idx): QT/KT/VT/OT: which*8192 + l*4096 + kb*512 + c*8 + j  (k=8kb+j)
//   W1T: 32768 + l*16384 + kb*2048 + f*8 + j      (kb 0..7)
//   W2T: 65536 + l*16384 + kb*512  + e*8 + j      (kb 0..31)
// ===========================================================================
__global__ __launch_bounds__(256) void prep_weights(
    const float* __restrict__ Wq, const float* __restrict__ Wk,
    const float* __restrict__ Wv, const float* __restrict__ Wo,
    const float* __restrict__ ff_w1, const float* __restrict__ ff_w2,
    unsigned short* __restrict__ wb)
{
  const int idx = blockIdx.x * 256 + threadIdx.x;   // < 98304
  float v;
  if (idx < 32768) {
    const int which = idx >> 13;
    const int r = idx & 8191;
    const int l = r >> 12, q = r & 4095;
    const int kb = q >> 9, c = (q >> 3) & 63, j = q & 7;
    const float* W = (which == 0) ? Wq : (which == 1) ? Wk : (which == 2) ? Wv : Wo;
    v = W[l*4096 + (8*kb + j)*64 + c];
  } else if (idx < 65536) {
    const int r = idx - 32768;
    const int l = r >> 14, q = r & 16383;
    const int kb = q >> 11, f = (q >> 3) & 255, j = q & 7;
    v = ff_w1[l*16384 + (8*kb + j)*256 + f];
  } else {
    const int r = idx - 65536;
    const int l = r >> 14, q = r & 16383;
    const int kb = q >> 9, e = (q >> 3) & 63, j = q & 7;
    v = ff_w2[l*16384 + (8*kb + j)*64 + e];
  }
  wb[idx] = bf16u(v);
}

// ===========================================================================
// Kernel A: GAT (8 heads) + conv1. One block per (b, n). Writes out0 bf16.
// ===========================================================================
#define A_GW 2484   // u32 xs_pk[12][207] then 96 floats of GAT params

__global__ __launch_bounds__(256) void gat_conv1_kernel(
    const float* __restrict__ x,        const int* __restrict__ adj,
    const float* __restrict__ gat_W2,   const float* __restrict__ gat_a,
    const float* __restrict__ gat_b,    const float* __restrict__ conv1_w,
    const float* __restrict__ conv1_b,  unsigned short* __restrict__ out0)
{
  __shared__ float lds[A_GW + 96];
  unsigned* au = (unsigned*)lds;

  const int bn   = blockIdx.x;
  const int b    = bn / NN;
  const int i    = bn % NN;
  const int tid  = threadIdx.x;
  const int lane = tid & 63;
  const int wid  = tid >> 6;

  const float* xb = x + b * 2 * NN * TT;
  for (int idx = tid; idx < NN * TT; idx += 256) {
    const int n = idx / TT, t = idx % TT;
    au[t * NN + n] = pk2(xb[idx], xb[NN * TT + idx]);
  }
  if (tid < 64) lds[A_GW + tid] = gat_W2[tid];
  if (tid < 16) { lds[A_GW + 64 + tid] = gat_a[tid]; lds[A_GW + 80 + tid] = gat_b[tid]; }
  __syncthreads();

  int   row0[4], row1[4];
  float aokf[4];
  {
    const int NSQ = NN * NN;
#pragma unroll
    for (int q = 0; q < 4; ++q) {
      const int j = lane + 64 * q;
      const int jj = (j < NN) ? j : 0;
      const int r0 = 2 * (i * NN + jj), r1 = r0 + 1;
      row0[q] = (r0 < NSQ) ? (r0 / NN) : ((r0 - NSQ) % NN);
      row1[q] = (r1 < NSQ) ? (r1 / NN) : ((r1 - NSQ) % NN);
      aokf[q] = ((j < NN) && adj[(b * NN + i) * NN + jj] > 0) ? 1.f : 0.f;
    }
  }

  float acc0[3] = {0.f, 0.f, 0.f}, acc1[3] = {0.f, 0.f, 0.f};
#pragma unroll
  for (int tk = 0; tk < 3; ++tk) {
    const int t = wid + 4 * tk;
    const unsigned* xst = au + t * NN;
    float xr00[4], xr01[4], xr10[4], xr11[4], xj0[4], xj1[4];
#pragma unroll
    for (int q = 0; q < 4; ++q) {
      int j = lane + 64 * q; if (j >= NN) j = 0;
      const unsigned u0 = xst[row0[q]], u1 = xst[row1[q]], uj = xst[j];
      xr00[q] = lo_f(u0); xr01[q] = hi_f(u0);
      xr10[q] = lo_f(u1); xr11[q] = hi_f(u1);
      xj0[q]  = lo_f(uj); xj1[q]  = hi_f(uj);
    }
#pragma unroll 1
    for (int h = 0; h < NGH; ++h) {
      const float w0 = lds[A_GW + h*8 + 0], w1_ = lds[A_GW + h*8 + 1];
      const float w2_= lds[A_GW + h*8 + 2], w3  = lds[A_GW + h*8 + 3];
      const float w4 = lds[A_GW + h*8 + 4], w5  = lds[A_GW + h*8 + 5];
      const float w6 = lds[A_GW + h*8 + 6], w7  = lds[A_GW + h*8 + 7];
      const float a0 = lds[A_GW + 64 + h*2], a1 = lds[A_GW + 64 + h*2 + 1];
      float ev[4];
#pragma unroll
      for (int q = 0; q < 4; ++q) {
        float wx0 = xr00[q]*w0 + xr01[q]*w2_ + xr10[q]*w4 + xr11[q]*w6;
        float wx1 = xr00[q]*w1_ + xr01[q]*w3 + xr10[q]*w5 + xr11[q]*w7;
        wx0 = (wx0 > 0.f) ? wx0 : GALPHA * wx0;
        wx1 = (wx1 > 0.f) ? wx1 : GALPHA * wx1;
        float e = a0 * wx0 + a1 * wx1;
        ev[q] = (aokf[q] > 0.f) ? e : GNEG;   // masked & invalid j -> GNEG; exp underflows to 0
      }
      float m = fmaxf(fmaxf(ev[0], ev[1]), fmaxf(ev[2], ev[3]));
      m = wred_max(m);
      float s0 = 0.f, s1 = 0.f, s2 = 0.f;
#pragma unroll
      for (int q = 0; q < 4; ++q) {
        const float ex = __expf(ev[q] - m);
        s0 += ex; s1 += ex * xj0[q]; s2 += ex * xj1[q];
      }
      s0 = wred_sum(s0); s1 = wred_sum(s1); s2 = wred_sum(s2);
      const float inv = 1.f / s0;
      acc0[tk] += tanh_fast(s1 * inv + lds[A_GW + 80 + h*2]);
      acc1[tk] += tanh_fast(s2 * inv + lds[A_GW + 80 + h*2 + 1]);
    }
  }

  // conv1 epilogue -> out0[bn][t][e] (bf16)
  {
    const float c1w0 = conv1_w[lane],       c1w1 = conv1_w[64 + lane];
    const float c1w2 = conv1_w[128 + lane], c1w3 = conv1_w[192 + lane];
    const float c1b  = conv1_b[lane];
#pragma unroll
    for (int tk = 0; tk < 3; ++tk) {
      const int t = wid + 4 * tk;
      const unsigned up = au[t * NN + i];
      const float g0 = acc0[tk] * (1.f / NGH), g1 = acc1[tk] * (1.f / NGH);
      out0[bn*768 + t*EE + lane] =
          bf16u(lo_f(up)*c1w0 + hi_f(up)*c1w1 + g0*c1w2 + g1*c1w3 + c1b);
    }
  }
}

// ===========================================================================
// Kernel B: 2-layer transformer + final convs. One block per (b,n).
// Wave owns t-triple {3w,3w+1,3w+2}; residual stream in registers.
// ===========================================================================
__global__ __launch_bounds__(256) void xf_final_kernel(
    const unsigned short* __restrict__ out0,  // bf16 (B,N,T,E)
    const unsigned short* __restrict__ wb,    // bf16 transposed weights (prep)
    const float* __restrict__ temb,
    const float* __restrict__ bo,
    const float* __restrict__ ln1_g, const float* __restrict__ ln1_b,
    const float* __restrict__ ln2_g, const float* __restrict__ ln2_b,
    const float* __restrict__ ff_b1, const float* __restrict__ ff_b2,
    const float* __restrict__ lng, const float* __restrict__ lnb,
    const float* __restrict__ conv2_w, const float* __restrict__ conv2_b,
    const float* __restrict__ conv3_w, const float* __restrict__ conv3_b,
    float* __restrict__ fout)
{
  __shared__ float lds[L_TOTB];
  unsigned*       au   = (unsigned*)lds;
  unsigned short* sh16 = (unsigned short*)lds;

  const int bn   = blockIdx.x;
  const int tid  = threadIdx.x;
  const int lane = tid & 63;
  const int wid  = tid >> 6;
  const int t0   = 3 * wid;

  float outv[3];
#pragma unroll
  for (int tt = 0; tt < 3; ++tt)
    outv[tt] = b16f(out0[bn*768 + (t0 + tt)*EE + lane]);

  for (int l = 0; l < 2; ++l) {
    const unsigned short* wqt = wb + l*4096;
    const unsigned short* wkt = wb + 8192  + l*4096;
    const unsigned short* wvt = wb + 16384 + l*4096;
    const unsigned short* wot = wb + 24576 + l*4096;
    const unsigned short* w1t = wb + 32768 + l*16384;
    const unsigned short* w2t = wb + 65536 + l*16384;

    __syncthreads();   // bar A: prior-layer FF reads done before QB-region writes

    // qq = out + temb (registers + LDS for cross-lane QKV reads)
    float qqv[3];
#pragma unroll
    for (int tt = 0; tt < 3; ++tt) {
      qqv[tt] = outv[tt] + temb[(t0 + tt)*EE + lane];
      lds[L_QQ + (t0 + tt)*SRD + lane] = qqv[tt];
    }

    // ---- QKV: lane owns col c, wave owns t-triple ----
    {
      const int c = lane;
      float aq[3] = {0,0,0}, ak[3] = {0,0,0}, av[3] = {0,0,0};
      const unsigned short* wqp = wqt + c*8;
      const unsigned short* wkp = wkt + c*8;
      const unsigned short* wvp = wvt + c*8;
#pragma unroll 1
      for (int kb = 0; kb < 8; ++kb) {
        const uint4 wq4 = *(const uint4*)(wqp + kb*512);
        const uint4 wk4 = *(const uint4*)(wkp + kb*512);
        const uint4 wv4 = *(const uint4*)(wvp + kb*512);
        float a[3][8];
#pragma unroll
        for (int tt = 0; tt < 3; ++tt) {
          *(float4*)&a[tt][0] = *(const float4*)&lds[L_QQ + (t0+tt)*SRD + 8*kb];
          *(float4*)&a[tt][4] = *(const float4*)&lds[L_QQ + (t0+tt)*SRD + 8*kb + 4];
        }
        float wf[8];
        UNPK8(wq4, wf);
#pragma unroll
        for (int tt = 0; tt < 3; ++tt)
#pragma unroll
          for (int j = 0; j < 8; ++j) aq[tt] += a[tt][j]*wf[j];
        UNPK8(wk4, wf);
#pragma unroll
        for (int tt = 0; tt < 3; ++tt)
#pragma unroll
          for (int j = 0; j < 8; ++j) ak[tt] += a[tt][j]*wf[j];
        UNPK8(wv4, wf);
#pragma unroll
        for (int tt = 0; tt < 3; ++tt)
#pragma unroll
          for (int j = 0; j < 8; ++j) av[tt] += a[tt][j]*wf[j];
      }
#pragma unroll
      for (int tt = 0; tt < 3; ++tt) {
        const int t = t0 + tt;
        sh16[2*L_QB + t*SRD16 + c] = bf16u(aq[tt]);
        sh16[2*L_KB + t*SRD16 + c] = bf16u(ak[tt]);
        sh16[2*L_VB + t*SRD16 + c] = bf16u(av[tt]);
      }
    }
    __syncthreads();   // bar B

    // ---- Attention: wave h owns head h (wave-local) ----
    {
      const int h = wid;
      if (lane < 48) {
        const int t = lane >> 2, s0 = 3*(lane & 3);
        float qf[16];
        {
          const uint4 qa = *(const uint4*)&sh16[2*L_QB + t*SRD16 + h*16];
          const uint4 qb = *(const uint4*)&sh16[2*L_QB + t*SRD16 + h*16 + 8];
          UNPK8(qa, qf); UNPK8(qb, qf + 8);
        }
#pragma unroll
        for (int ss = 0; ss < 3; ++ss) {
          const int s = s0 + ss;
          float d = 0.f;
          {
            const uint4 ka = *(const uint4*)&sh16[2*L_KB + s*SRD16 + h*16];
            float kf[8]; UNPK8(ka, kf);
#pragma unroll
            for (int xq = 0; xq < 8; ++xq) d += qf[xq]*kf[xq];
          }
          {
            const uint4 kc = *(const uint4*)&sh16[2*L_KB + s*SRD16 + h*16 + 8];
            float kf[8]; UNPK8(kc, kf);
#pragma unroll
            for (int xq = 0; xq < 8; ++xq) d += qf[8+xq]*kf[xq];
          }
          lds[L_SC + h*144 + t*12 + s] = d * 0.25f;
        }
      }
      __builtin_amdgcn_wave_barrier();
      if (lane < 12) {
        float* row = &lds[L_SC + h*144 + lane*12];
        float m = row[0];
#pragma unroll
        for (int s = 1; s < 12; ++s) m = fmaxf(m, row[s]);
        float ex[12]; float sum = 0.f;
#pragma unroll
        for (int s = 0; s < 12; ++s) { ex[s] = __expf(row[s] - m); sum += ex[s]; }
        const float inv = 1.f / sum;
#pragma unroll
        for (int s = 0; s < 12; ++s) row[s] = ex[s] * inv;
      }
      __builtin_amdgcn_wave_barrier();
      {
        const int d = lane & 15, tq = lane >> 4;
#pragma unroll
        for (int tt = 0; tt < 3; ++tt) {
          const int t = tq + 4*tt;
          float cacc = 0.f;
#pragma unroll
          for (int s = 0; s < 12; ++s) {
            const float p = lds[L_SC + h*144 + t*12 + s];
            const unsigned uv = au[L_VB + s*36 + h*8 + (d >> 1)];
            cacc += p * ((d & 1) ? hi_f(uv) : lo_f(uv));
          }
          lds[L_CTX + t*SRD + h*16 + d] = cacc;
        }
      }
    }
    __syncthreads();   // bar C

    // ---- Wo + bias + residual(qq) -> LN1 -> X1 (wave-local after bar C) ----
    {
      float acc[3] = {0,0,0};
      const unsigned short* wop = wot + lane*8;
#pragma unroll 1
      for (int kb = 0; kb < 8; ++kb) {
        const uint4 w4 = *(const uint4*)(wop + kb*512);
        float a[3][8];
#pragma unroll
        for (int tt = 0; tt < 3; ++tt) {
          *(float4*)&a[tt][0] = *(const float4*)&lds[L_CTX + (t0+tt)*SRD + 8*kb];
          *(float4*)&a[tt][4] = *(const float4*)&lds[L_CTX + (t0+tt)*SRD + 8*kb + 4];
        }
        float wf[8]; UNPK8(w4, wf);
#pragma unroll
        for (int tt = 0; tt < 3; ++tt)
#pragma unroll
          for (int j = 0; j < 8; ++j) acc[tt] += a[tt][j]*wf[j];
      }
#pragma unroll
      for (int tt = 0; tt < 3; ++tt) {
        float v = acc[tt] + bo[l*EE + lane] + qqv[tt];
        const float mu = wred_sum(v) * (1.f/64);
        const float dd = v - mu;
        const float var = wred_sum(dd*dd) * (1.f/64);
        lds[L_X1 + (t0+tt)*SRD + lane] =
            dd * rsqrtf(var + 1e-5f) * ln1_g[l*EE + lane] + ln1_b[l*EE + lane];
      }
    }
    __syncthreads();   // bar D: all CTX reads done before FF clobbers the region

    // ---- FF1 + relu -> FF (f32) : lane owns f-quad, wave owns t-triple ----
    {
      const int f0 = 4*lane;
      float ac[4][3] = {};
#pragma unroll 1
      for (int kb = 0; kb < 8; ++kb) {
        uint4 w4[4];
#pragma unroll
        for (int ff = 0; ff < 4; ++ff)
          w4[ff] = *(const uint4*)(w1t + kb*2048 + (f0+ff)*8);
        float a[3][8];
#pragma unroll
        for (int tt = 0; tt < 3; ++tt) {
          *(float4*)&a[tt][0] = *(const float4*)&lds[L_X1 + (t0+tt)*SRD + 8*kb];
          *(float4*)&a[tt][4] = *(const float4*)&lds[L_X1 + (t0+tt)*SRD + 8*kb + 4];
        }
#pragma unroll
        for (int ff = 0; ff < 4; ++ff) {
          float wf[8]; UNPK8(w4[ff], wf);
#pragma unroll
          for (int tt = 0; tt < 3; ++tt)
#pragma unroll
            for (int j = 0; j < 8; ++j) ac[ff][tt] += a[tt][j]*wf[j];
        }
      }
      const float4 bv = *(const float4*)&ff_b1[l*FFD + f0];
#pragma unroll
      for (int tt = 0; tt < 3; ++tt) {
        *(float4*)&lds[L_FF + (t0+tt)*FSRD + f0] = make_float4(
            fmaxf(ac[0][tt] + bv.x, 0.f), fmaxf(ac[1][tt] + bv.y, 0.f),
            fmaxf(ac[2][tt] + bv.z, 0.f), fmaxf(ac[3][tt] + bv.w, 0.f));
      }
    }
    // FF1 -> FF2 is wave-local (same wave wrote all 256 f of its t-triple)

    // ---- FF2 + b2 + residual(X1) -> LN2 -> +out -> LN3 (all wave-local) ----
    {
      float acc[3] = {0,0,0};
      const unsigned short* w2p = w2t + lane*8;
#pragma unroll 1
      for (int kb = 0; kb < 32; ++kb) {
        const uint4 w4 = *(const uint4*)(w2p + kb*512);
        float a[3][8];
#pragma unroll
        for (int tt = 0; tt < 3; ++tt) {
          *(float4*)&a[tt][0] = *(const float4*)&lds[L_FF + (t0+tt)*FSRD + 8*kb];
          *(float4*)&a[tt][4] = *(const float4*)&lds[L_FF + (t0+tt)*FSRD + 8*kb + 4];
        }
        float wf[8]; UNPK8(w4, wf);
#pragma unroll
        for (int tt = 0; tt < 3; ++tt)
#pragma unroll
          for (int j = 0; j < 8; ++j) acc[tt] += a[tt][j]*wf[j];
      }
#pragma unroll
      for (int tt = 0; tt < 3; ++tt) {
        float v = acc[tt] + ff_b2[l*EE + lane] + lds[L_X1 + (t0+tt)*SRD + lane];
        float mu = wred_sum(v) * (1.f/64);
        float dd = v - mu;
        float var = wred_sum(dd*dd) * (1.f/64);
        const float blk = dd * rsqrtf(var + 1e-5f) * ln2_g[l*EE + lane] + ln2_b[l*EE + lane];
        float w = blk + outv[tt];
        mu = wred_sum(w) * (1.f/64);
        dd = w - mu;
        var = wred_sum(dd*dd) * (1.f/64);
        outv[tt] = dd * rsqrtf(var + 1e-5f) * lng[l*EE + lane] + lnb[l*EE + lane];
      }
    }
  }

  // stage final residual stream (QQ region is free; no FF overlap)
#pragma unroll
  for (int tt = 0; tt < 3; ++tt)
    lds[L_QQ + (t0+tt)*SRD + lane] = outv[tt];
  __syncthreads();

  // final conv2 (time mix) + relu + conv3 (embed contraction)
  float xt[12];
#pragma unroll
  for (int t = 0; t < 12; ++t) xt[t] = lds[L_QQ + t*SRD + lane];
  const float c3w = conv3_w[lane];
  for (int o = wid; o < 12; o += 4) {
    float a = conv2_b[o];
#pragma unroll
    for (int t = 0; t < 12; ++t) a += xt[t] * conv2_w[o*TT + t];
    a = fmaxf(a, 0.f);
    const float s = wred_sum(a * c3w);
    if (lane == 0) fout[bn*TT + o] = s + conv3_b[0];
  }
}

// ---------------------------------------------------------------------------
extern "C" void kernel_launch(void* const* d_in, const int* in_sizes, int n_in,
                              void* d_out, int out_size, void* d_ws, size_t ws_size,
                              hipStream_t stream) {
  const float* x       = (const float*)d_in[0];
  const int*   adj     = (const int*)  d_in[1];
  const float* gat_W2  = (const float*)d_in[2];
  const float* gat_a   = (const float*)d_in[3];
  const float* gat_b   = (const float*)d_in[4];
  const float* conv1_w = (const float*)d_in[5];
  const float* conv1_b = (const float*)d_in[6];
  const float* temb    = (const float*)d_in[7];
  const float* Wq      = (const float*)d_in[8];
  const float* Wk      = (const float*)d_in[9];
  const float* Wv      = (const float*)d_in[10];
  const float* Wo      = (const float*)d_in[11];
  const float* bo      = (const float*)d_in[12];
  const float* ln1_g   = (const float*)d_in[13];
  const float* ln1_b   = (const float*)d_in[14];
  const float* ln2_g   = (const float*)d_in[15];
  const float* ln2_b   = (const float*)d_in[16];
  const float* ff_w1   = (const float*)d_in[17];
  const float* ff_b1   = (const float*)d_in[18];
  const float* ff_w2   = (const float*)d_in[19];
  const float* ff_b2   = (const float*)d_in[20];
  const float* lng     = (const float*)d_in[21];
  const float* lnb     = (const float*)d_in[22];
  const float* conv2_w = (const float*)d_in[23];
  const float* conv2_b = (const float*)d_in[24];
  const float* conv3_w = (const float*)d_in[25];
  const float* conv3_b = (const float*)d_in[26];

  unsigned short* wb   = (unsigned short*)d_ws;          // 98304 u16
  unsigned short* out0 = wb + 98304;                     // 8*207*768 u16 bf16
  float* fout = (float*)d_out;

  prep_weights<<<384, 256, 0, stream>>>(Wq, Wk, Wv, Wo, ff_w1, ff_w2, wb);

  gat_conv1_kernel<<<BB*NN, 256, 0, stream>>>(
      x, adj, gat_W2, gat_a, gat_b, conv1_w, conv1_b, out0);

  xf_final_kernel<<<BB*NN, 256, 0, stream>>>(
      out0, wb, temb, bo, ln1_g, ln1_b, ln2_g, ln2_b,
      ff_b1, ff_b2, lng, lnb, conv2_w, conv2_b, conv3_w, conv3_b, fout);
}